// Round 12
// baseline (1086.598 us; speedup 1.0000x reference)
//
#include <hip/hip_runtime.h>

#define Hdim 128
#define NN 10000
#define NE 320000
#define NEPAD 320064    // 1667 * 192
#define NG 16
#define EB 192          // edge rows per block (4 waves x 48 rows) -> 3 blocks/CU
#define EBX 64          // xs rows per block (4 waves x 16 rows)
#define NB 16           // node rows per block; 4 waves N-split
#define SXO 136         // LDS bf16 row stride

typedef __attribute__((ext_vector_type(8))) short bf8;   // 8 bf16 = 4 VGPRs
typedef __attribute__((ext_vector_type(4))) float f4;
#define MFMA16 __builtin_amdgcn_mfma_f32_16x16x32_bf16

#if __has_builtin(__builtin_amdgcn_exp2f)
#define EXP2F(x) __builtin_amdgcn_exp2f(x)
#else
#define EXP2F(x) exp2f(x)
#endif
#if __has_builtin(__builtin_amdgcn_rcpf)
#define RCPF(x) __builtin_amdgcn_rcpf(x)
#else
#define RCPF(x) (1.0f/(x))
#endif

__device__ __forceinline__ float fsigm(float x){
    return RCPF(1.0f + EXP2F(-1.442695041f*x));
}
__device__ __forceinline__ float ftanh(float x){
    float t = EXP2F(2.885390082f*x);          // e^(2x)
    return 1.0f - 2.0f*RCPF(t + 1.0f);        // (t-1)/(t+1)
}

__device__ __forceinline__ unsigned short f2bf(float v){
    unsigned int b = __float_as_uint(v);
    return (unsigned short)((b + 0x7FFFu + ((b>>16)&1u)) >> 16);
}
__device__ __forceinline__ float bf2f(unsigned short u){
    return __uint_as_float(((unsigned int)u)<<16);
}

__device__ __forceinline__ bf8 load_frag_f32(const float* __restrict__ p){
    float4 a = *(const float4*)p;
    float4 b = *(const float4*)(p+4);
    bf8 f;
    f[0]=(short)f2bf(a.x); f[1]=(short)f2bf(a.y); f[2]=(short)f2bf(a.z); f[3]=(short)f2bf(a.w);
    f[4]=(short)f2bf(b.x); f[5]=(short)f2bf(b.y); f[6]=(short)f2bf(b.z); f[7]=(short)f2bf(b.w);
    return f;
}

__device__ __forceinline__ bf8 load_pb(const unsigned short* __restrict__ P,
                                       int ntile, int ksteps, int kstep, int lane){
    return *(const bf8*)(P + ((((ntile*ksteps + kstep)<<6) + lane)<<3));
}

// ---------------------------------------------------------------- pack all B mats
struct PackJob { const float* s0; const float* s1; int ld, coloff, kr0, ktot, cnt, base; };
struct PackJobs { PackJob j[10]; };

__global__ __launch_bounds__(256) void pack_all(PackJobs P, unsigned short* __restrict__ dst)
{
    int idx = blockIdx.x*256 + threadIdx.x;
    #pragma unroll
    for (int t=0; t<10; ++t){
        int lo = P.j[t].base, hi = lo + P.j[t].cnt;
        if (idx >= lo && idx < hi){
            int l = idx - lo;
            int e    = l & 7;
            int lane = (l >> 3) & 63;
            int kt   = l >> 9;
            int ksteps = P.j[t].ktot >> 5;
            int ntile = kt / ksteps, kstep = kt - ntile*ksteps;
            int k = kstep*32 + ((lane>>4)<<3) + e;
            int n = ntile*16 + (lane&15);
            const float* S = (k < P.j[t].kr0) ? P.j[t].s0 : P.j[t].s1;
            int kk = (k < P.j[t].kr0) ? k : (k - P.j[t].kr0);
            dst[idx] = f2bf(S[(long)kk*P.j[t].ld + P.j[t].coloff + n]);
        }
    }
}

// ---------------------------------------------------------------- edge sort by dst
__global__ void hist_count(const int* __restrict__ dst, const int* __restrict__ batch,
                           int* __restrict__ histo, float* __restrict__ cnt){
    int e = blockIdx.x*256 + threadIdx.x;
    if (e < NE) atomicAdd(&histo[dst[e]], 1);
    if (e < NN) atomicAdd(&cnt[batch[e]], 1.0f);
}

__global__ __launch_bounds__(256) void scan_kernel(const int* __restrict__ histo,
                                                   int* __restrict__ cursor){
    __shared__ int ls[256];
    int t = threadIdx.x;
    int s = 0;
    #pragma unroll 8
    for (int i=0;i<40;++i){ int idx = t*40+i; if (idx < NN) s += histo[idx]; }
    ls[t] = s; __syncthreads();
    for (int off=1; off<256; off<<=1){
        int v = ls[t];
        if (t >= off) v += ls[t-off];
        __syncthreads();
        ls[t] = v; __syncthreads();
    }
    int run = ls[t] - s;
    for (int i=0;i<40;++i){
        int idx = t*40+i;
        if (idx < NN){ cursor[idx] = run; run += histo[idx]; }
    }
}

// fills sorted arrays; pad slots [NE, NEPAD) get src=0, dst=NN (agg dump row)
__global__ void scatter_kernel(const int* __restrict__ src, const int* __restrict__ dst,
                               int* __restrict__ cursor,
                               int* __restrict__ ssrc, int* __restrict__ sdst,
                               int* __restrict__ perm){
    int e = blockIdx.x*256 + threadIdx.x;
    if (e < NE){
        int d = dst[e];
        int p = atomicAdd(&cursor[d], 1);
        ssrc[p] = src[e]; sdst[p] = d; perm[p] = e;
    } else if (e < NEPAD){
        ssrc[e] = 0; sdst[e] = NN;
    }
}

// ---------------------------------------------------------------- all f32->bf16 converts
// pad ea rows [NE, NEPAD) are zeroed for determinism
__global__ __launch_bounds__(256) void conv_all(
    const float* __restrict__ ea_i, const int* __restrict__ perm,
    const float* __restrict__ x, const float* __restrict__ u,
    unsigned short* __restrict__ ea, unsigned short* __restrict__ xb,
    float* __restrict__ ucur)
{
    long idx = (long)blockIdx.x*256 + threadIdx.x;
    const long GE = (long)NEPAD*16;
    const long GX = GE + (long)NN*16;
    if (idx < GE){
        long row = idx>>4; int c8 = (int)(idx&15);
        if (row < NE){
            long srow = perm[row];
            *(bf8*)(ea + row*Hdim + c8*8) = load_frag_f32(ea_i + srow*Hdim + c8*8);
        } else {
            bf8 z = {0,0,0,0,0,0,0,0};
            *(bf8*)(ea + row*Hdim + c8*8) = z;
        }
    } else if (idx < GX){
        long i2 = idx - GE; long row = i2>>4; int c8 = (int)(i2&15);
        *(bf8*)(xb + row*Hdim + c8*8) = load_frag_f32(x + row*Hdim + c8*8);
    } else {
        int i3 = (int)(idx - GX);   // 0..255
        *(float4*)(ucur + i3*8)   = *(const float4*)(u + i3*8);
        *(float4*)(ucur + i3*8+4) = *(const float4*)(u + i3*8+4);
    }
}

// ------------------------------------------- initial gu/nu (t=0), zero xsum
__global__ __launch_bounds__(128) void graph_pre_kernel(
    const float* __restrict__ u, const float* __restrict__ We, const float* __restrict__ be,
    const float* __restrict__ Wn, const float* __restrict__ bn,
    float* __restrict__ gu, float* __restrict__ nu, float* __restrict__ xsum)
{
    __shared__ float sU[Hdim];
    int b = blockIdx.x, which = b>>4, g = b&15, j = threadIdx.x;
    sU[j] = u[g*Hdim + j];
    if (b == 0){
        #pragma unroll
        for (int q=0;q<NG;++q) xsum[q*Hdim + j] = 0.f;
    }
    __syncthreads();
    const float* W = which ? (Wn + 256*Hdim) : (We + 384*Hdim);
    float a0 = which ? bn[j] : be[j], a1=0.f, a2=0.f, a3=0.f;
    for (int k=0;k<Hdim;k+=4){
        a0 = fmaf(sU[k+0], W[(k+0)*Hdim+j], a0);
        a1 = fmaf(sU[k+1], W[(k+1)*Hdim+j], a1);
        a2 = fmaf(sU[k+2], W[(k+2)*Hdim+j], a2);
        a3 = fmaf(sU[k+3], W[(k+3)*Hdim+j], a3);
    }
    (which ? nu : gu)[g*Hdim + j] = (a0+a1)+(a2+a3);
}

// ------------------------------------------- xs1g (bf16) = x@We1 + gu[batch]; zero agg
__global__ __launch_bounds__(256,4) void xs_mfma(
    const unsigned short* __restrict__ xb, const unsigned short* __restrict__ PXS,
    const float* __restrict__ gu, const int* __restrict__ batch,
    unsigned short* __restrict__ xs1g, float* __restrict__ agg)
{
    int tid = threadIdx.x, lane = tid&63, wave = tid>>6;
    int nbB = blockIdx.x*EBX;
    int nb = nbB + wave*16;
    {
        long base = (long)nbB*Hdim;
        #pragma unroll
        for (int q=0;q<8;++q){
            long off = base + q*1024 + tid*4;
            if ((off>>7) < NN+1) *(float4*)(agg+off) = make_float4(0.f,0.f,0.f,0.f);
        }
    }
    int arow = lane&15, kg = lane>>4;
    int col = lane&15, crow = kg*4;
    bf8 xF[4];
    {
        int row = nb + arow; if (row > NN-1) row = NN-1;
        #pragma unroll
        for (int ks=0;ks<4;++ks)
            xF[ks] = *(const bf8*)(xb + (long)row*Hdim + ks*32 + kg*8);
    }
    int g0[4];
    #pragma unroll
    for (int r=0;r<4;++r){
        int ra = nb + crow + r; if (ra > NN-1) ra = NN-1;
        g0[r] = batch[ra];
    }
    #pragma unroll 2
    for (int nt=0; nt<8; ++nt){
        f4 acc = {0.f,0.f,0.f,0.f};
        #pragma unroll
        for (int ks=0;ks<4;++ks){
            bf8 b = load_pb(PXS, nt, 4, ks, lane);
            acc = MFMA16(xF[ks], b, acc, 0,0,0);
        }
        int j = nt*16 + col;
        #pragma unroll
        for (int r=0;r<4;++r){
            int row0 = nb + crow + r;
            if (row0 < NN) xs1g[(long)row0*Hdim + j] = f2bf(acc[r] + gu[g0[r]*Hdim + j]);
        }
    }
}

// ------------------------------------------- fused edge model + edge GRU (dst-sorted)
// round-8 structure at EB=192: 4 waves x 48 exclusive rows, 3 blocks/CU
__global__ __launch_bounds__(256,3) void edge_mfma(
    unsigned short* __restrict__ ea,
    const unsigned short* __restrict__ xs1g, const unsigned short* __restrict__ xb,
    const unsigned short* __restrict__ PW1, const unsigned short* __restrict__ PX2,
    const unsigned short* __restrict__ PRZ,
    const unsigned short* __restrict__ PNI, const unsigned short* __restrict__ PNH,
    const float* __restrict__ bih, const float* __restrict__ bhh,
    const int* __restrict__ ssrc, const int* __restrict__ sdst,
    float* __restrict__ agg)
{
    __shared__ __align__(16) unsigned short sEo[EB*SXO];   // 52224 B
    __shared__ int sS[EB], sD[EB];
    int tid = threadIdx.x, lane = tid&63, wave = tid>>6;
    long eb = (long)blockIdx.x*EB;
    if (tid < EB){ sS[tid] = ssrc[eb+tid]; sD[tid] = sdst[eb+tid]; }
    __syncthreads();
    int r0 = wave*48;
    int arow = lane&15, kg = lane>>4;
    int col = lane&15, crow = kg*4;
    bf8 eaF[3][4], xdF[3][4];
    #pragma unroll
    for (int m=0;m<3;++m){
        int lr = r0 + m*16 + arow;
        long drow = sD[lr];
        #pragma unroll
        for (int ks=0;ks<4;++ks){
            eaF[m][ks] = *(const bf8*)(ea + (eb + lr)*Hdim + ks*32 + kg*8);
            xdF[m][ks] = *(const bf8*)(xb + drow*Hdim + ks*32 + kg*8);
        }
    }
    // phase1: eo = relu(ea@We3 + xb[dst]@We2 + xs1g[src])
    #pragma unroll 1
    for (int nt=0; nt<8; ++nt){
        int j = nt*16 + col;
        f4 acc[3];
        #pragma unroll
        for (int m=0;m<3;++m) acc[m] = (f4){0.f,0.f,0.f,0.f};
        #pragma unroll
        for (int ks=0;ks<4;++ks){
            bf8 b = load_pb(PW1, nt, 4, ks, lane);
            #pragma unroll
            for (int m=0;m<3;++m) acc[m] = MFMA16(eaF[m][ks], b, acc[m], 0,0,0);
        }
        #pragma unroll
        for (int ks=0;ks<4;++ks){
            bf8 b = load_pb(PX2, nt, 4, ks, lane);
            #pragma unroll
            for (int m=0;m<3;++m) acc[m] = MFMA16(xdF[m][ks], b, acc[m], 0,0,0);
        }
        #pragma unroll
        for (int m=0;m<3;++m)
            #pragma unroll
            for (int r=0;r<4;++r){
                int lr = r0 + m*16 + crow + r;
                float x1 = bf2f(xs1g[(long)sS[lr]*Hdim + j]);
                sEo[lr*SXO + j] = f2bf(fmaxf(acc[m][r] + x1, 0.f));
            }
    }
    bf8 eoF[3][4];
    #pragma unroll
    for (int m=0;m<3;++m)
        #pragma unroll
        for (int ks=0;ks<4;++ks)
            eoF[m][ks] = *(const bf8*)(sEo + (r0 + m*16 + arow)*SXO + ks*32 + kg*8);
    // stash h (eaF) over the dead eo buffer (same-wave rows, proven pattern)
    #pragma unroll
    for (int m=0;m<3;++m)
        #pragma unroll
        for (int ks=0;ks<4;++ks)
            *(bf8*)(sEo + (r0 + m*16 + arow)*SXO + ks*32 + kg*8) = eaF[m][ks];
    // gates -> write new state to sEo only
    #pragma unroll 1
    for (int nt=0; nt<8; ++nt){
        int j = nt*16 + col;
        float vr = bih[j] + bhh[j];
        float vz = bih[128+j] + bhh[128+j];
        float vi = bih[256+j], vh = bhh[256+j];
        f4 ar[3], az[3], ai[3], ah[3];
        #pragma unroll
        for (int m=0;m<3;++m){
            ar[m] = (f4){vr,vr,vr,vr}; az[m] = (f4){vz,vz,vz,vz};
            ai[m] = (f4){vi,vi,vi,vi}; ah[m] = (f4){vh,vh,vh,vh};
        }
        #pragma unroll
        for (int ks=0;ks<8;++ks){
            bf8 bR = load_pb(PRZ, nt,   8, ks, lane);
            bf8 bZ = load_pb(PRZ, nt+8, 8, ks, lane);
            #pragma unroll
            for (int m=0;m<3;++m){
                bf8 A = (ks<4) ? eoF[m][ks] : eaF[m][ks-4];
                ar[m] = MFMA16(A, bR, ar[m], 0,0,0);
                az[m] = MFMA16(A, bZ, az[m], 0,0,0);
            }
        }
        #pragma unroll
        for (int ks=0;ks<4;++ks){
            bf8 bI = load_pb(PNI, nt, 4, ks, lane);
            bf8 bH = load_pb(PNH, nt, 4, ks, lane);
            #pragma unroll
            for (int m=0;m<3;++m){
                ai[m] = MFMA16(eoF[m][ks], bI, ai[m], 0,0,0);
                ah[m] = MFMA16(eaF[m][ks], bH, ah[m], 0,0,0);
            }
        }
        #pragma unroll
        for (int m=0;m<3;++m)
            #pragma unroll
            for (int r=0;r<4;++r){
                int lr = r0 + m*16 + crow + r;
                float h  = bf2f(sEo[lr*SXO + j]);   // h from LDS stash
                float rr = fsigm(ar[m][r]);
                float zz = fsigm(az[m][r]);
                float nn = ftanh(fmaf(rr, ah[m][r], ai[m][r]));
                float o  = fmaf(zz, h - nn, nn);
                sEo[lr*SXO + j] = f2bf(o);          // overwrite h (same owner)
            }
    }
    __syncthreads();
    // bulk coalesced write of new state: full rows, full cache lines
    {
        #pragma unroll
        for (int q=0;q<12;++q){
            int idx = q*256 + tid;
            int row = idx >> 4, c8 = idx & 15;
            *(bf8*)(ea + (eb + row)*Hdim + c8*8) = *(const bf8*)(sEo + row*SXO + c8*8);
        }
    }
    // segmented column-sum over sorted dst runs
    {
        int j = tid & 127;
        int half = tid >> 7;
        int lo = half*96, hi = lo + 96;
        float acc = 0.f;
        for (int row=lo; row<hi; ++row){
            acc += bf2f(sEo[row*SXO + j]);
            bool flush = (row == hi-1) || (sD[row] != sD[row+1]);
            if (flush){
                atomicAdd(&agg[(long)sD[row]*Hdim + j], acc);
                acc = 0.f;
            }
        }
    }
}

// ------------------------------------------- fused node model + node GRU (N-split)
__global__ __launch_bounds__(256,4) void node_mfma(
    unsigned short* __restrict__ xb, const float* __restrict__ agg,
    const float* __restrict__ nu,
    const unsigned short* __restrict__ PP1, const unsigned short* __restrict__ PRZ,
    const unsigned short* __restrict__ PNI, const unsigned short* __restrict__ PNH,
    const float* __restrict__ bih, const float* __restrict__ bhh,
    const int* __restrict__ batch, float* __restrict__ xsum)
{
    __shared__ __align__(16) unsigned short sXo[NB*SXO];   // 4352 B
    __shared__ int sG[NB];
    int tid = threadIdx.x, lane = tid&63, wave = tid>>6;
    int nb = blockIdx.x*NB;
    if (tid < NB){
        int row = nb + tid; if (row > NN-1) row = NN-1;
        sG[tid] = batch[row];
    }
    __syncthreads();
    int arow = lane&15, kg = lane>>4;
    int col = lane&15, crow = kg*4;
    bf8 xF[4], agF[4];
    {
        int row = nb + arow; if (row > NN-1) row = NN-1;
        #pragma unroll
        for (int ks=0;ks<4;++ks){
            xF[ks]  = *(const bf8*)(xb + (long)row*Hdim + ks*32 + kg*8);
            agF[ks] = load_frag_f32(agg + (long)row*Hdim + ks*32 + kg*8);
        }
    }
    // phase1: xo = relu([x|agg]@Wn[0:256] + nu[g]) for this wave's 2 nt tiles
    #pragma unroll
    for (int q=0;q<2;++q){
        int nt = wave*2 + q;
        int j = nt*16 + col;
        f4 acc = {0.f,0.f,0.f,0.f};
        #pragma unroll
        for (int ks=0;ks<8;++ks){
            bf8 A = (ks<4) ? xF[ks] : agF[ks-4];
            bf8 b = load_pb(PP1, nt, 8, ks, lane);
            acc = MFMA16(A, b, acc, 0,0,0);
        }
        #pragma unroll
        for (int r=0;r<4;++r){
            float nv = nu[sG[crow + r]*Hdim + j];
            sXo[(crow + r)*SXO + j] = f2bf(fmaxf(acc[r] + nv, 0.f));
        }
    }
    __syncthreads();                       // B1: xo complete
    bf8 xoF[4];
    #pragma unroll
    for (int ks=0;ks<4;++ks)
        xoF[ks] = *(const bf8*)(sXo + arow*SXO + ks*32 + kg*8);
    __syncthreads();                       // B2: xoF reads done
    // h-stash: wave w writes k-slice w from its xF registers
    *(bf8*)(sXo + arow*SXO + wave*32 + kg*8) = xF[wave];
    __syncthreads();                       // B3: h stash complete
    #pragma unroll
    for (int q=0;q<2;++q){
        int nt = wave*2 + q;
        int j = nt*16 + col;
        float vr = bih[j] + bhh[j];
        float vz = bih[128+j] + bhh[128+j];
        float vi = bih[256+j], vh = bhh[256+j];
        f4 ar = {vr,vr,vr,vr}, az = {vz,vz,vz,vz};
        f4 ai = {vi,vi,vi,vi}, ah = {vh,vh,vh,vh};
        #pragma unroll
        for (int ks=0;ks<8;++ks){
            bf8 A = (ks<4) ? xoF[ks] : xF[ks-4];
            bf8 bR = load_pb(PRZ, nt,   8, ks, lane);
            bf8 bZ = load_pb(PRZ, nt+8, 8, ks, lane);
            ar = MFMA16(A, bR, ar, 0,0,0);
            az = MFMA16(A, bZ, az, 0,0,0);
        }
        #pragma unroll
        for (int ks=0;ks<4;++ks){
            bf8 bI = load_pb(PNI, nt, 4, ks, lane);
            bf8 bH = load_pb(PNH, nt, 4, ks, lane);
            ai = MFMA16(xoF[ks], bI, ai, 0,0,0);
            ah = MFMA16(xF[ks],  bH, ah, 0,0,0);
        }
        #pragma unroll
        for (int r=0;r<4;++r){
            int lr = crow + r;
            int row = nb + lr;
            unsigned short ob = 0;
            if (row < NN){
                float h  = bf2f(sXo[lr*SXO + j]);
                float rr = fsigm(ar[r]);
                float zz = fsigm(az[r]);
                float nn = ftanh(fmaf(rr, ah[r], ai[r]));
                float o  = fmaf(zz, h - nn, nn);
                ob = f2bf(o);
            }
            sXo[lr*SXO + j] = ob;
        }
    }
    __syncthreads();                       // B4
    // bulk coalesced write of new node state (16 rows x 16 chunks = 1/thread)
    {
        int row = tid >> 4, c8 = tid & 15;
        int grow = nb + row;
        if (grow < NN)
            *(bf8*)(xb + (long)grow*Hdim + c8*8) = *(const bf8*)(sXo + row*SXO + c8*8);
    }
    // segmented column-sum over sorted batch runs -> xsum
    {
        int j = tid & 127;
        int half = tid >> 7;
        int lo = half*8, hi = lo + 8;
        float acc = 0.f;
        for (int row=lo; row<hi; ++row){
            acc += bf2f(sXo[row*SXO + j]);
            bool flush = (row == hi-1) || (sG[row] != sG[row+1]);
            if (flush){
                atomicAdd(&xsum[sG[row]*Hdim + j], acc);
                acc = 0.f;
            }
        }
    }
}

// ------------------------------------------- global model + GRU + next-step gu/nu
__global__ __launch_bounds__(128) void global_kernel(
    float* __restrict__ xsum, const float* __restrict__ cnt,
    float* __restrict__ u,
    const float* __restrict__ Wg, const float* __restrict__ bg,
    const float* __restrict__ Wih, const float* __restrict__ Whh,
    const float* __restrict__ bih, const float* __restrict__ bhh,
    const float* __restrict__ We, const float* __restrict__ be,
    const float* __restrict__ Wn, const float* __restrict__ bn,
    float* __restrict__ gu, float* __restrict__ nu,
    float* __restrict__ out, int step)
{
    __shared__ float sXm[Hdim], sU[Hdim], sUo[Hdim], sO[Hdim];
    int g = blockIdx.x, j = threadIdx.x;
    float inv = 1.0f / fmaxf(cnt[g], 1.0f);
    sXm[j] = xsum[g*Hdim + j] * inv;
    xsum[g*Hdim + j] = 0.f;
    float hj = u[g*Hdim + j];
    sU[j] = hj;
    __syncthreads();
    {
        float a0=bg[j], a1=0.f, a2=0.f, a3=0.f;
        for (int k=0;k<Hdim;k+=4){
            a0 = fmaf(sXm[k+0], Wg[(k+0)*Hdim + j], a0);
            a1 = fmaf(sXm[k+1], Wg[(k+1)*Hdim + j], a1);
            a2 = fmaf(sXm[k+2], Wg[(k+2)*Hdim + j], a2);
            a3 = fmaf(sXm[k+3], Wg[(k+3)*Hdim + j], a3);
            a0 = fmaf(sU[k+0],  Wg[(128+k+0)*Hdim + j], a0);
            a1 = fmaf(sU[k+1],  Wg[(128+k+1)*Hdim + j], a1);
            a2 = fmaf(sU[k+2],  Wg[(128+k+2)*Hdim + j], a2);
            a3 = fmaf(sU[k+3],  Wg[(128+k+3)*Hdim + j], a3);
        }
        sUo[j] = fmaxf((a0+a1)+(a2+a3), 0.f);
    }
    __syncthreads();
    float o;
    {
        float r[4]  = {bih[j]+bhh[j], 0.f, 0.f, 0.f};
        float z[4]  = {bih[128+j]+bhh[128+j], 0.f, 0.f, 0.f};
        float ni[4] = {bih[256+j], 0.f, 0.f, 0.f};
        float nh[4] = {bhh[256+j], 0.f, 0.f, 0.f};
        for (int k=0;k<Hdim;k+=4){
            #pragma unroll
            for (int q=0;q<4;++q){
                float in = sUo[k+q], h = sU[k+q];
                r[q]  = fmaf(in, Wih[(k+q)*384 + j],       r[q]);
                r[q]  = fmaf(h,  Whh[(k+q)*384 + j],       r[q]);
                z[q]  = fmaf(in, Wih[(k+q)*384 + 128 + j], z[q]);
                z[q]  = fmaf(h,  Whh[(k+q)*384 + 128 + j], z[q]);
                ni[q] = fmaf(in, Wih[(k+q)*384 + 256 + j], ni[q]);
                nh[q] = fmaf(h,  Whh[(k+q)*384 + 256 + j], nh[q]);
            }
        }
        float rr = fsigm((r[0]+r[1])+(r[2]+r[3]));
        float zz = fsigm((z[0]+z[1])+(z[2]+z[3]));
        float n  = ftanh(fmaf(rr, (nh[0]+nh[1])+(nh[2]+nh[3]),
                                  (ni[0]+ni[1])+(ni[2]+ni[3])));
        o = fmaf(zz, hj - n, n);
        u[g*Hdim + j] = o;
        out[(long)(g*3 + step)*Hdim + j] = o;
        sO[j] = o;
    }
    __syncthreads();
    {
        float a0=be[j], a1=0.f, b0=bn[j], b1=0.f;
        for (int k=0;k<Hdim;k+=2){
            float v0 = sO[k], v1 = sO[k+1];
            a0 = fmaf(v0, We[(384+k)*Hdim + j],   a0);
            a1 = fmaf(v1, We[(384+k+1)*Hdim + j], a1);
            b0 = fmaf(v0, Wn[(256+k)*Hdim + j],   b0);
            b1 = fmaf(v1, Wn[(256+k+1)*Hdim + j], b1);
        }
        gu[g*Hdim + j] = a0+a1;
        nu[g*Hdim + j] = b0+b1;
    }
}

// ---------------------------------------------------------------- host
extern "C" void kernel_launch(void* const* d_in, const int* in_sizes, int n_in,
                              void* d_out, int out_size, void* d_ws, size_t ws_size,
                              hipStream_t stream)
{
    const float* x    = (const float*)d_in[0];
    const float* ea_i = (const float*)d_in[1];
    const float* u    = (const float*)d_in[2];
    const float* We   = (const float*)d_in[3];
    const float* be   = (const float*)d_in[4];
    const float* Wn   = (const float*)d_in[5];
    const float* bn   = (const float*)d_in[6];
    const float* Wg   = (const float*)d_in[7];
    const float* bg   = (const float*)d_in[8];
    const float* eWih = (const float*)d_in[9];
    const float* eWhh = (const float*)d_in[10];
    const float* ebih = (const float*)d_in[11];
    const float* ebhh = (const float*)d_in[12];
    const float* nWih = (const float*)d_in[13];
    const float* nWhh = (const float*)d_in[14];
    const float* nbih = (const float*)d_in[15];
    const float* nbhh = (const float*)d_in[16];
    const float* gWih = (const float*)d_in[17];
    const float* gWhh = (const float*)d_in[18];
    const float* gbih = (const float*)d_in[19];
    const float* gbhh = (const float*)d_in[20];
    const int*   ei   = (const int*)d_in[21];
    const int*   batch= (const int*)d_in[22];
    const int* src = ei;
    const int* dst = ei + NE;
    float* out = (float*)d_out;

    size_t off = 0;
    auto alloc = [&](size_t bytes)->char*{
        char* p = (char*)d_ws + off;
        off += (bytes + 255) & ~(size_t)255;
        return p;
    };
    unsigned short* ea   = (unsigned short*)alloc((size_t)NEPAD*Hdim*2);
    unsigned short* xb   = (unsigned short*)alloc((size_t)(NN+1)*Hdim*2);
    unsigned short* xs1g = (unsigned short*)alloc((size_t)NN*Hdim*2);
    float*          agg  = (float*)alloc((size_t)(NN+1)*Hdim*4);   // row NN = pad dump
    float*          ucur = (float*)alloc((size_t)NG*Hdim*4);
    float*          gu   = (float*)alloc((size_t)NG*Hdim*4);
    float*          nu   = (float*)alloc((size_t)NG*Hdim*4);
    float*          xsum = (float*)alloc((size_t)NG*Hdim*4);
    unsigned short* PK   = (unsigned short*)alloc((size_t)278528*2);
    int* histo  = (int*)alloc((size_t)(NN+NG)*4);
    float* cnt  = (float*)(histo + NN);
    int* cursor = (int*)alloc((size_t)NN*4);
    int* ssrc   = (int*)alloc((size_t)NEPAD*4);
    int* sdst   = (int*)alloc((size_t)NEPAD*4);
    int* perm   = (int*)alloc((size_t)NE*4);

    unsigned short* PXS  = PK + 0;        // We1
    unsigned short* PX2  = PK + 16384;    // We2
    unsigned short* PW1  = PK + 32768;    // We3
    unsigned short* PeRZ = PK + 49152;
    unsigned short* PeNI = PK + 114688;
    unsigned short* PeNH = PK + 131072;
    unsigned short* PnP1 = PK + 147456;
    unsigned short* PnRZ = PK + 180224;
    unsigned short* PnNI = PK + 245760;
    unsigned short* PnNH = PK + 262144;

    hipMemsetAsync(histo, 0, (size_t)(NN+NG)*4, stream);
    hist_count<<<(NE+255)/256, 256, 0, stream>>>(dst, batch, histo, cnt);
    scan_kernel<<<1, 256, 0, stream>>>(histo, cursor);
    scatter_kernel<<<(NEPAD+255)/256, 256, 0, stream>>>(src, dst, cursor, ssrc, sdst, perm);
    {
        long groups = (long)(NEPAD+NN+NG)*16;
        conv_all<<<(int)((groups+255)/256), 256, 0, stream>>>(ea_i, perm, x, u, ea, xb, ucur);
    }

    PackJobs PJ;
    auto setj = [&](int t, const float* s0, const float* s1, int ld, int coloff,
                    int kr0, int ktot, int ntot, int base){
        PJ.j[t] = PackJob{ s0, s1, ld, coloff, kr0, ktot, ktot*ntot, base };
    };
    setj(0, We,            We,   Hdim, 0,   128, 128, 128, 0);
    setj(1, We+128*Hdim,   We,   Hdim, 0,   128, 128, 128, 16384);
    setj(2, We+256*Hdim,   We,   Hdim, 0,   128, 128, 128, 32768);
    setj(3, eWih, eWhh, 384, 0,   128, 256, 256, 49152);
    setj(4, eWih, eWih, 384, 256, 128, 128, 128, 114688);
    setj(5, eWhh, eWhh, 384, 256, 128, 128, 128, 131072);
    setj(6, Wn,   Wn,   Hdim, 0,  256, 256, 128, 147456);
    setj(7, nWih, nWhh, 384, 0,   128, 256, 256, 180224);
    setj(8, nWih, nWih, 384, 256, 128, 128, 128, 245760);
    setj(9, nWhh, nWhh, 384, 256, 128, 128, 128, 262144);
    pack_all<<<278528/256, 256, 0, stream>>>(PJ, PK);

    graph_pre_kernel<<<32, 128, 0, stream>>>(ucur, We, be, Wn, bn, gu, nu, xsum);

    for (int t=0; t<3; ++t){
        xs_mfma<<<(NN+EBX-1)/EBX, 256, 0, stream>>>(xb, PXS, gu, batch, xs1g, agg);
        edge_mfma<<<NEPAD/EB, 256, 0, stream>>>(ea, xs1g, xb, PW1, PX2, PeRZ, PeNI, PeNH,
                                                ebih, ebhh, ssrc, sdst, agg);
        node_mfma<<<(NN+NB-1)/NB, 256, 0, stream>>>(xb, agg, nu, PnP1, PnRZ, PnNI, PnNH,
                                                    nbih, nbhh, batch, xsum);
        global_kernel<<<NG, 128, 0, stream>>>(xsum, cnt, ucur, Wg, bg,
                                              gWih, gWhh, gbih, gbhh,
                                              We, be, Wn, bn, gu, nu, out, t);
    }
}

// Round 13
// 928.994 us; speedup vs baseline: 1.1696x; 1.1696x over previous
//
#include <hip/hip_runtime.h>

#define Hdim 128
#define NN 10000
#define NE 320000
#define NG 16
#define EB 256          // edge rows per block (4 waves x 64 rows) -- proven optimum (r8/r11)
#define EBX 64          // xs rows per block (4 waves x 16 rows)
#define NB 16           // node rows per block; 4 waves N-split (L2-resident working set)
#define SXO 136         // LDS bf16 row stride

typedef __attribute__((ext_vector_type(8))) short bf8;   // 8 bf16 = 4 VGPRs
typedef __attribute__((ext_vector_type(4))) float f4;
#define MFMA16 __builtin_amdgcn_mfma_f32_16x16x32_bf16

#if __has_builtin(__builtin_amdgcn_exp2f)
#define EXP2F(x) __builtin_amdgcn_exp2f(x)
#else
#define EXP2F(x) exp2f(x)
#endif
#if __has_builtin(__builtin_amdgcn_rcpf)
#define RCPF(x) __builtin_amdgcn_rcpf(x)
#else
#define RCPF(x) (1.0f/(x))
#endif

__device__ __forceinline__ float fsigm(float x){
    return RCPF(1.0f + EXP2F(-1.442695041f*x));
}
__device__ __forceinline__ float ftanh(float x){
    float t = EXP2F(2.885390082f*x);          // e^(2x)
    return 1.0f - 2.0f*RCPF(t + 1.0f);        // (t-1)/(t+1)
}

__device__ __forceinline__ unsigned short f2bf(float v){
    unsigned int b = __float_as_uint(v);
    return (unsigned short)((b + 0x7FFFu + ((b>>16)&1u)) >> 16);
}
__device__ __forceinline__ float bf2f(unsigned short u){
    return __uint_as_float(((unsigned int)u)<<16);
}

__device__ __forceinline__ bf8 load_frag_f32(const float* __restrict__ p){
    float4 a = *(const float4*)p;
    float4 b = *(const float4*)(p+4);
    bf8 f;
    f[0]=(short)f2bf(a.x); f[1]=(short)f2bf(a.y); f[2]=(short)f2bf(a.z); f[3]=(short)f2bf(a.w);
    f[4]=(short)f2bf(b.x); f[5]=(short)f2bf(b.y); f[6]=(short)f2bf(b.z); f[7]=(short)f2bf(b.w);
    return f;
}

__device__ __forceinline__ bf8 load_pb(const unsigned short* __restrict__ P,
                                       int ntile, int ksteps, int kstep, int lane){
    return *(const bf8*)(P + ((((ntile*ksteps + kstep)<<6) + lane)<<3));
}

// ---------------------------------------------------------------- pack all B mats
struct PackJob { const float* s0; const float* s1; int ld, coloff, kr0, ktot, cnt, base; };
struct PackJobs { PackJob j[10]; };

__global__ __launch_bounds__(256) void pack_all(PackJobs P, unsigned short* __restrict__ dst)
{
    int idx = blockIdx.x*256 + threadIdx.x;
    #pragma unroll
    for (int t=0; t<10; ++t){
        int lo = P.j[t].base, hi = lo + P.j[t].cnt;
        if (idx >= lo && idx < hi){
            int l = idx - lo;
            int e    = l & 7;
            int lane = (l >> 3) & 63;
            int kt   = l >> 9;
            int ksteps = P.j[t].ktot >> 5;
            int ntile = kt / ksteps, kstep = kt - ntile*ksteps;
            int k = kstep*32 + ((lane>>4)<<3) + e;
            int n = ntile*16 + (lane&15);
            const float* S = (k < P.j[t].kr0) ? P.j[t].s0 : P.j[t].s1;
            int kk = (k < P.j[t].kr0) ? k : (k - P.j[t].kr0);
            dst[idx] = f2bf(S[(long)kk*P.j[t].ld + P.j[t].coloff + n]);
        }
    }
}

// ---------------------------------------------------------------- edge sort by dst
__global__ void hist_count(const int* __restrict__ dst, const int* __restrict__ batch,
                           int* __restrict__ histo, float* __restrict__ cnt){
    int e = blockIdx.x*256 + threadIdx.x;
    if (e < NE) atomicAdd(&histo[dst[e]], 1);
    if (e < NN) atomicAdd(&cnt[batch[e]], 1.0f);
}

__global__ __launch_bounds__(256) void scan_kernel(const int* __restrict__ histo,
                                                   int* __restrict__ cursor){
    __shared__ int ls[256];
    int t = threadIdx.x;
    int s = 0;
    #pragma unroll 8
    for (int i=0;i<40;++i){ int idx = t*40+i; if (idx < NN) s += histo[idx]; }
    ls[t] = s; __syncthreads();
    for (int off=1; off<256; off<<=1){
        int v = ls[t];
        if (t >= off) v += ls[t-off];
        __syncthreads();
        ls[t] = v; __syncthreads();
    }
    int run = ls[t] - s;
    for (int i=0;i<40;++i){
        int idx = t*40+i;
        if (idx < NN){ cursor[idx] = run; run += histo[idx]; }
    }
}

__global__ void scatter_kernel(const int* __restrict__ src, const int* __restrict__ dst,
                               int* __restrict__ cursor,
                               int* __restrict__ ssrc, int* __restrict__ sdst,
                               int* __restrict__ perm){
    int e = blockIdx.x*256 + threadIdx.x;
    if (e < NE){
        int d = dst[e];
        int p = atomicAdd(&cursor[d], 1);
        ssrc[p] = src[e]; sdst[p] = d; perm[p] = e;
    }
}

// ---------------------------------------------------------------- all f32->bf16 converts
__global__ __launch_bounds__(256) void conv_all(
    const float* __restrict__ ea_i, const int* __restrict__ perm,
    const float* __restrict__ x, const float* __restrict__ u,
    unsigned short* __restrict__ ea, unsigned short* __restrict__ xb,
    float* __restrict__ ucur)
{
    long idx = (long)blockIdx.x*256 + threadIdx.x;
    const long GE = (long)NE*16;
    const long GX = GE + (long)NN*16;
    if (idx < GE){
        long row = idx>>4; int c8 = (int)(idx&15);
        long srow = perm[row];
        *(bf8*)(ea + row*Hdim + c8*8) = load_frag_f32(ea_i + srow*Hdim + c8*8);
    } else if (idx < GX){
        long i2 = idx - GE; long row = i2>>4; int c8 = (int)(i2&15);
        *(bf8*)(xb + row*Hdim + c8*8) = load_frag_f32(x + row*Hdim + c8*8);
    } else {
        int i3 = (int)(idx - GX);   // 0..255
        *(float4*)(ucur + i3*8)   = *(const float4*)(u + i3*8);
        *(float4*)(ucur + i3*8+4) = *(const float4*)(u + i3*8+4);
    }
}

// ------------------------------------------- initial gu/nu (t=0), zero xsum
__global__ __launch_bounds__(128) void graph_pre_kernel(
    const float* __restrict__ u, const float* __restrict__ We, const float* __restrict__ be,
    const float* __restrict__ Wn, const float* __restrict__ bn,
    float* __restrict__ gu, float* __restrict__ nu, float* __restrict__ xsum)
{
    __shared__ float sU[Hdim];
    int b = blockIdx.x, which = b>>4, g = b&15, j = threadIdx.x;
    sU[j] = u[g*Hdim + j];
    if (b == 0){
        #pragma unroll
        for (int q=0;q<NG;++q) xsum[q*Hdim + j] = 0.f;
    }
    __syncthreads();
    const float* W = which ? (Wn + 256*Hdim) : (We + 384*Hdim);
    float a0 = which ? bn[j] : be[j], a1=0.f, a2=0.f, a3=0.f;
    for (int k=0;k<Hdim;k+=4){
        a0 = fmaf(sU[k+0], W[(k+0)*Hdim+j], a0);
        a1 = fmaf(sU[k+1], W[(k+1)*Hdim+j], a1);
        a2 = fmaf(sU[k+2], W[(k+2)*Hdim+j], a2);
        a3 = fmaf(sU[k+3], W[(k+3)*Hdim+j], a3);
    }
    (which ? nu : gu)[g*Hdim + j] = (a0+a1)+(a2+a3);
}

// ------------------------------------------- xs1g (bf16) = x@We1 + gu[batch]; zero agg
__global__ __launch_bounds__(256,4) void xs_mfma(
    const unsigned short* __restrict__ xb, const unsigned short* __restrict__ PXS,
    const float* __restrict__ gu, const int* __restrict__ batch,
    unsigned short* __restrict__ xs1g, float* __restrict__ agg)
{
    int tid = threadIdx.x, lane = tid&63, wave = tid>>6;
    int nbB = blockIdx.x*EBX;
    int nb = nbB + wave*16;
    {
        long base = (long)nbB*Hdim;
        #pragma unroll
        for (int q=0;q<8;++q){
            long off = base + q*1024 + tid*4;
            if ((off>>7) < NN) *(float4*)(agg+off) = make_float4(0.f,0.f,0.f,0.f);
        }
    }
    int arow = lane&15, kg = lane>>4;
    int col = lane&15, crow = kg*4;
    bf8 xF[4];
    {
        int row = nb + arow; if (row > NN-1) row = NN-1;
        #pragma unroll
        for (int ks=0;ks<4;++ks)
            xF[ks] = *(const bf8*)(xb + (long)row*Hdim + ks*32 + kg*8);
    }
    int g0[4];
    #pragma unroll
    for (int r=0;r<4;++r){
        int ra = nb + crow + r; if (ra > NN-1) ra = NN-1;
        g0[r] = batch[ra];
    }
    #pragma unroll 2
    for (int nt=0; nt<8; ++nt){
        f4 acc = {0.f,0.f,0.f,0.f};
        #pragma unroll
        for (int ks=0;ks<4;++ks){
            bf8 b = load_pb(PXS, nt, 4, ks, lane);
            acc = MFMA16(xF[ks], b, acc, 0,0,0);
        }
        int j = nt*16 + col;
        #pragma unroll
        for (int r=0;r<4;++r){
            int row0 = nb + crow + r;
            if (row0 < NN) xs1g[(long)row0*Hdim + j] = f2bf(acc[r] + gu[g0[r]*Hdim + j]);
        }
    }
}

// ------------------------------------------- fused edge model + edge GRU (dst-sorted)
// proven r8/r11 structure: 4 waves x 64 exclusive rows, h stashed in LDS, bulk write
__global__ __launch_bounds__(256,2) void edge_mfma(
    unsigned short* __restrict__ ea,
    const unsigned short* __restrict__ xs1g, const unsigned short* __restrict__ xb,
    const unsigned short* __restrict__ PW1, const unsigned short* __restrict__ PX2,
    const unsigned short* __restrict__ PRZ,
    const unsigned short* __restrict__ PNI, const unsigned short* __restrict__ PNH,
    const float* __restrict__ bih, const float* __restrict__ bhh,
    const int* __restrict__ ssrc, const int* __restrict__ sdst,
    float* __restrict__ agg)
{
    __shared__ __align__(16) unsigned short sEo[EB*SXO];   // 69632 B
    __shared__ int sS[EB], sD[EB];
    int tid = threadIdx.x, lane = tid&63, wave = tid>>6;
    long eb = (long)blockIdx.x*EB;
    sS[tid] = ssrc[eb+tid]; sD[tid] = sdst[eb+tid];
    __syncthreads();
    int r0 = wave*64;
    int arow = lane&15, kg = lane>>4;
    int col = lane&15, crow = kg*4;
    bf8 eaF[4][4], xdF[4][4];
    #pragma unroll
    for (int m=0;m<4;++m){
        int lr = r0 + m*16 + arow;
        long drow = sD[lr];
        #pragma unroll
        for (int ks=0;ks<4;++ks){
            eaF[m][ks] = *(const bf8*)(ea + (eb + lr)*Hdim + ks*32 + kg*8);
            xdF[m][ks] = *(const bf8*)(xb + drow*Hdim + ks*32 + kg*8);
        }
    }
    // phase1: eo = relu(ea@We3 + xb[dst]@We2 + xs1g[src])
    #pragma unroll 1
    for (int nt=0; nt<8; ++nt){
        int j = nt*16 + col;
        f4 acc[4];
        #pragma unroll
        for (int m=0;m<4;++m) acc[m] = (f4){0.f,0.f,0.f,0.f};
        #pragma unroll
        for (int ks=0;ks<4;++ks){
            bf8 b = load_pb(PW1, nt, 4, ks, lane);
            #pragma unroll
            for (int m=0;m<4;++m) acc[m] = MFMA16(eaF[m][ks], b, acc[m], 0,0,0);
        }
        #pragma unroll
        for (int ks=0;ks<4;++ks){
            bf8 b = load_pb(PX2, nt, 4, ks, lane);
            #pragma unroll
            for (int m=0;m<4;++m) acc[m] = MFMA16(xdF[m][ks], b, acc[m], 0,0,0);
        }
        #pragma unroll
        for (int m=0;m<4;++m)
            #pragma unroll
            for (int r=0;r<4;++r){
                int lr = r0 + m*16 + crow + r;
                float x1 = bf2f(xs1g[(long)sS[lr]*Hdim + j]);
                sEo[lr*SXO + j] = f2bf(fmaxf(acc[m][r] + x1, 0.f));
            }
    }
    bf8 eoF[4][4];
    #pragma unroll
    for (int m=0;m<4;++m)
        #pragma unroll
        for (int ks=0;ks<4;++ks)
            eoF[m][ks] = *(const bf8*)(sEo + (r0 + m*16 + arow)*SXO + ks*32 + kg*8);
    // stash h (eaF) over the dead eo buffer (same-wave rows, proven pattern)
    #pragma unroll
    for (int m=0;m<4;++m)
        #pragma unroll
        for (int ks=0;ks<4;++ks)
            *(bf8*)(sEo + (r0 + m*16 + arow)*SXO + ks*32 + kg*8) = eaF[m][ks];
    // gates -> write new state to sEo only
    #pragma unroll 1
    for (int nt=0; nt<8; ++nt){
        int j = nt*16 + col;
        float vr = bih[j] + bhh[j];
        float vz = bih[128+j] + bhh[128+j];
        float vi = bih[256+j], vh = bhh[256+j];
        f4 ar[4], az[4], ai[4], ah[4];
        #pragma unroll
        for (int m=0;m<4;++m){
            ar[m] = (f4){vr,vr,vr,vr}; az[m] = (f4){vz,vz,vz,vz};
            ai[m] = (f4){vi,vi,vi,vi}; ah[m] = (f4){vh,vh,vh,vh};
        }
        #pragma unroll
        for (int ks=0;ks<8;++ks){
            bf8 bR = load_pb(PRZ, nt,   8, ks, lane);
            bf8 bZ = load_pb(PRZ, nt+8, 8, ks, lane);
            #pragma unroll
            for (int m=0;m<4;++m){
                bf8 A = (ks<4) ? eoF[m][ks] : eaF[m][ks-4];
                ar[m] = MFMA16(A, bR, ar[m], 0,0,0);
                az[m] = MFMA16(A, bZ, az[m], 0,0,0);
            }
        }
        #pragma unroll
        for (int ks=0;ks<4;++ks){
            bf8 bI = load_pb(PNI, nt, 4, ks, lane);
            bf8 bH = load_pb(PNH, nt, 4, ks, lane);
            #pragma unroll
            for (int m=0;m<4;++m){
                ai[m] = MFMA16(eoF[m][ks], bI, ai[m], 0,0,0);
                ah[m] = MFMA16(eaF[m][ks], bH, ah[m], 0,0,0);
            }
        }
        #pragma unroll
        for (int m=0;m<4;++m)
            #pragma unroll
            for (int r=0;r<4;++r){
                int lr = r0 + m*16 + crow + r;
                float h  = bf2f(sEo[lr*SXO + j]);   // h from LDS stash
                float rr = fsigm(ar[m][r]);
                float zz = fsigm(az[m][r]);
                float nn = ftanh(fmaf(rr, ah[m][r], ai[m][r]));
                float o  = fmaf(zz, h - nn, nn);
                sEo[lr*SXO + j] = f2bf(o);          // overwrite h (same owner)
            }
    }
    __syncthreads();
    // bulk coalesced write of new state: full rows, full cache lines
    {
        #pragma unroll
        for (int q=0;q<16;++q){
            int idx = q*256 + tid;
            int row = idx >> 4, c8 = idx & 15;
            *(bf8*)(ea + (eb + row)*Hdim + c8*8) = *(const bf8*)(sEo + row*SXO + c8*8);
        }
    }
    // segmented column-sum over sorted dst runs
    {
        int j = tid & 127;
        int half = tid >> 7;
        int lo = half*128, hi = lo + 128;
        float acc = 0.f;
        for (int row=lo; row<hi; ++row){
            acc += bf2f(sEo[row*SXO + j]);
            bool flush = (row == hi-1) || (sD[row] != sD[row+1]);
            if (flush){
                atomicAdd(&agg[(long)sD[row]*Hdim + j], acc);
                acc = 0.f;
            }
        }
    }
}

// ------------------------------------------- fused node model + node GRU (N-split)
// block = 16 rows, wave w handles nt = 2w, 2w+1; working set L2-resident
__global__ __launch_bounds__(256,4) void node_mfma(
    unsigned short* __restrict__ xb, const float* __restrict__ agg,
    const float* __restrict__ nu,
    const unsigned short* __restrict__ PP1, const unsigned short* __restrict__ PRZ,
    const unsigned short* __restrict__ PNI, const unsigned short* __restrict__ PNH,
    const float* __restrict__ bih, const float* __restrict__ bhh,
    const int* __restrict__ batch, float* __restrict__ xsum)
{
    __shared__ __align__(16) unsigned short sXo[NB*SXO];   // 4352 B
    __shared__ int sG[NB];
    int tid = threadIdx.x, lane = tid&63, wave = tid>>6;
    int nb = blockIdx.x*NB;
    if (tid < NB){
        int row = nb + tid; if (row > NN-1) row = NN-1;
        sG[tid] = batch[row];
    }
    __syncthreads();
    int arow = lane&15, kg = lane>>4;
    int col = lane&15, crow = kg*4;
    bf8 xF[4], agF[4];
    {
        int row = nb + arow; if (row > NN-1) row = NN-1;
        #pragma unroll
        for (int ks=0;ks<4;++ks){
            xF[ks]  = *(const bf8*)(xb + (long)row*Hdim + ks*32 + kg*8);
            agF[ks] = load_frag_f32(agg + (long)row*Hdim + ks*32 + kg*8);
        }
    }
    // phase1: xo = relu([x|agg]@Wn[0:256] + nu[g]) for this wave's 2 nt tiles
    #pragma unroll
    for (int q=0;q<2;++q){
        int nt = wave*2 + q;
        int j = nt*16 + col;
        f4 acc = {0.f,0.f,0.f,0.f};
        #pragma unroll
        for (int ks=0;ks<8;++ks){
            bf8 A = (ks<4) ? xF[ks] : agF[ks-4];
            bf8 b = load_pb(PP1, nt, 8, ks, lane);
            acc = MFMA16(A, b, acc, 0,0,0);
        }
        #pragma unroll
        for (int r=0;r<4;++r){
            float nv = nu[sG[crow + r]*Hdim + j];
            sXo[(crow + r)*SXO + j] = f2bf(fmaxf(acc[r] + nv, 0.f));
        }
    }
    __syncthreads();                       // B1: xo complete
    bf8 xoF[4];
    #pragma unroll
    for (int ks=0;ks<4;++ks)
        xoF[ks] = *(const bf8*)(sXo + arow*SXO + ks*32 + kg*8);
    __syncthreads();                       // B2: xoF reads done
    // h-stash: wave w writes k-slice w from its xF registers
    *(bf8*)(sXo + arow*SXO + wave*32 + kg*8) = xF[wave];
    __syncthreads();                       // B3: h stash complete
    #pragma unroll
    for (int q=0;q<2;++q){
        int nt = wave*2 + q;
        int j = nt*16 + col;
        float vr = bih[j] + bhh[j];
        float vz = bih[128+j] + bhh[128+j];
        float vi = bih[256+j], vh = bhh[256+j];
        f4 ar = {vr,vr,vr,vr}, az = {vz,vz,vz,vz};
        f4 ai = {vi,vi,vi,vi}, ah = {vh,vh,vh,vh};
        #pragma unroll
        for (int ks=0;ks<8;++ks){
            bf8 A = (ks<4) ? xoF[ks] : xF[ks-4];
            bf8 bR = load_pb(PRZ, nt,   8, ks, lane);
            bf8 bZ = load_pb(PRZ, nt+8, 8, ks, lane);
            ar = MFMA16(A, bR, ar, 0,0,0);
            az = MFMA16(A, bZ, az, 0,0,0);
        }
        #pragma unroll
        for (int ks=0;ks<4;++ks){
            bf8 bI = load_pb(PNI, nt, 4, ks, lane);
            bf8 bH = load_pb(PNH, nt, 4, ks, lane);
            ai = MFMA16(xoF[ks], bI, ai, 0,0,0);
            ah = MFMA16(xF[ks],  bH, ah, 0,0,0);
        }
        #pragma unroll
        for (int r=0;r<4;++r){
            int lr = crow + r;
            int row = nb + lr;
            unsigned short ob = 0;
            if (row < NN){
                float h  = bf2f(sXo[lr*SXO + j]);
                float rr = fsigm(ar[r]);
                float zz = fsigm(az[r]);
                float nn = ftanh(fmaf(rr, ah[r], ai[r]));
                float o  = fmaf(zz, h - nn, nn);
                ob = f2bf(o);
            }
            sXo[lr*SXO + j] = ob;
        }
    }
    __syncthreads();                       // B4
    // bulk coalesced write of new node state (16 rows x 16 chunks = 1/thread)
    {
        int row = tid >> 4, c8 = tid & 15;
        int grow = nb + row;
        if (grow < NN)
            *(bf8*)(xb + (long)grow*Hdim + c8*8) = *(const bf8*)(sXo + row*SXO + c8*8);
    }
    // segmented column-sum over sorted batch runs -> xsum
    {
        int j = tid & 127;
        int half = tid >> 7;
        int lo = half*8, hi = lo + 8;
        float acc = 0.f;
        for (int row=lo; row<hi; ++row){
            acc += bf2f(sXo[row*SXO + j]);
            bool flush = (row == hi-1) || (sG[row] != sG[row+1]);
            if (flush){
                atomicAdd(&xsum[sG[row]*Hdim + j], acc);
                acc = 0.f;
            }
        }
    }
}

// ------------------------------------------- global model + GRU + next-step gu/nu
__global__ __launch_bounds__(128) void global_kernel(
    float* __restrict__ xsum, const float* __restrict__ cnt,
    float* __restrict__ u,
    const float* __restrict__ Wg, const float* __restrict__ bg,
    const float* __restrict__ Wih, const float* __restrict__ Whh,
    const float* __restrict__ bih, const float* __restrict__ bhh,
    const float* __restrict__ We, const float* __restrict__ be,
    const float* __restrict__ Wn, const float* __restrict__ bn,
    float* __restrict__ gu, float* __restrict__ nu,
    float* __restrict__ out, int step)
{
    __shared__ float sXm[Hdim], sU[Hdim], sUo[Hdim], sO[Hdim];
    int g = blockIdx.x, j = threadIdx.x;
    float inv = 1.0f / fmaxf(cnt[g], 1.0f);
    sXm[j] = xsum[g*Hdim + j] * inv;
    xsum[g*Hdim + j] = 0.f;
    float hj = u[g*Hdim + j];
    sU[j] = hj;
    __syncthreads();
    {
        float a0=bg[j], a1=0.f, a2=0.f, a3=0.f;
        for (int k=0;k<Hdim;k+=4){
            a0 = fmaf(sXm[k+0], Wg[(k+0)*Hdim + j], a0);
            a1 = fmaf(sXm[k+1], Wg[(k+1)*Hdim + j], a1);
            a2 = fmaf(sXm[k+2], Wg[(k+2)*Hdim + j], a2);
            a3 = fmaf(sXm[k+3], Wg[(k+3)*Hdim + j], a3);
            a0 = fmaf(sU[k+0],  Wg[(128+k+0)*Hdim + j], a0);
            a1 = fmaf(sU[k+1],  Wg[(128+k+1)*Hdim + j], a1);
            a2 = fmaf(sU[k+2],  Wg[(128+k+2)*Hdim + j], a2);
            a3 = fmaf(sU[k+3],  Wg[(128+k+3)*Hdim + j], a3);
        }
        sUo[j] = fmaxf((a0+a1)+(a2+a3), 0.f);
    }
    __syncthreads();
    float o;
    {
        float r[4]  = {bih[j]+bhh[j], 0.f, 0.f, 0.f};
        float z[4]  = {bih[128+j]+bhh[128+j], 0.f, 0.f, 0.f};
        float ni[4] = {bih[256+j], 0.f, 0.f, 0.f};
        float nh[4] = {bhh[256+j], 0.f, 0.f, 0.f};
        for (int k=0;k<Hdim;k+=4){
            #pragma unroll
            for (int q=0;q<4;++q){
                float in = sUo[k+q], h = sU[k+q];
                r[q]  = fmaf(in, Wih[(k+q)*384 + j],       r[q]);
                r[q]  = fmaf(h,  Whh[(k+q)*384 + j],       r[q]);
                z[q]  = fmaf(in, Wih[(k+q)*384 + 128 + j], z[q]);
                z[q]  = fmaf(h,  Whh[(k+q)*384 + 128 + j], z[q]);
                ni[q] = fmaf(in, Wih[(k+q)*384 + 256 + j], ni[q]);
                nh[q] = fmaf(h,  Whh[(k+q)*384 + 256 + j], nh[q]);
            }
        }
        float rr = fsigm((r[0]+r[1])+(r[2]+r[3]));
        float zz = fsigm((z[0]+z[1])+(z[2]+z[3]));
        float n  = ftanh(fmaf(rr, (nh[0]+nh[1])+(nh[2]+nh[3]),
                                  (ni[0]+ni[1])+(ni[2]+ni[3])));
        o = fmaf(zz, hj - n, n);
        u[g*Hdim + j] = o;
        out[(long)(g*3 + step)*Hdim + j] = o;
        sO[j] = o;
    }
    __syncthreads();
    {
        float a0=be[j], a1=0.f, b0=bn[j], b1=0.f;
        for (int k=0;k<Hdim;k+=2){
            float v0 = sO[k], v1 = sO[k+1];
            a0 = fmaf(v0, We[(384+k)*Hdim + j],   a0);
            a1 = fmaf(v1, We[(384+k+1)*Hdim + j], a1);
            b0 = fmaf(v0, Wn[(256+k)*Hdim + j],   b0);
            b1 = fmaf(v1, Wn[(256+k+1)*Hdim + j], b1);
        }
        gu[g*Hdim + j] = a0+a1;
        nu[g*Hdim + j] = b0+b1;
    }
}

// ---------------------------------------------------------------- host
extern "C" void kernel_launch(void* const* d_in, const int* in_sizes, int n_in,
                              void* d_out, int out_size, void* d_ws, size_t ws_size,
                              hipStream_t stream)
{
    const float* x    = (const float*)d_in[0];
    const float* ea_i = (const float*)d_in[1];
    const float* u    = (const float*)d_in[2];
    const float* We   = (const float*)d_in[3];
    const float* be   = (const float*)d_in[4];
    const float* Wn   = (const float*)d_in[5];
    const float* bn   = (const float*)d_in[6];
    const float* Wg   = (const float*)d_in[7];
    const float* bg   = (const float*)d_in[8];
    const float* eWih = (const float*)d_in[9];
    const float* eWhh = (const float*)d_in[10];
    const float* ebih = (const float*)d_in[11];
    const float* ebhh = (const float*)d_in[12];
    const float* nWih = (const float*)d_in[13];
    const float* nWhh = (const float*)d_in[14];
    const float* nbih = (const float*)d_in[15];
    const float* nbhh = (const float*)d_in[16];
    const float* gWih = (const float*)d_in[17];
    const float* gWhh = (const float*)d_in[18];
    const float* gbih = (const float*)d_in[19];
    const float* gbhh = (const float*)d_in[20];
    const int*   ei   = (const int*)d_in[21];
    const int*   batch= (const int*)d_in[22];
    const int* src = ei;
    const int* dst = ei + NE;
    float* out = (float*)d_out;

    size_t off = 0;
    auto alloc = [&](size_t bytes)->char*{
        char* p = (char*)d_ws + off;
        off += (bytes + 255) & ~(size_t)255;
        return p;
    };
    unsigned short* ea   = (unsigned short*)alloc((size_t)NE*Hdim*2);
    unsigned short* xb   = (unsigned short*)alloc((size_t)NN*Hdim*2);
    unsigned short* xs1g = (unsigned short*)alloc((size_t)NN*Hdim*2);
    float*          agg  = (float*)alloc((size_t)NN*Hdim*4);
    float*          ucur = (float*)alloc((size_t)NG*Hdim*4);
    float*          gu   = (float*)alloc((size_t)NG*Hdim*4);
    float*          nu   = (float*)alloc((size_t)NG*Hdim*4);
    float*          xsum = (float*)alloc((size_t)NG*Hdim*4);
    unsigned short* PK   = (unsigned short*)alloc((size_t)278528*2);
    int* histo  = (int*)alloc((size_t)(NN+NG)*4);
    float* cnt  = (float*)(histo + NN);
    int* cursor = (int*)alloc((size_t)NN*4);
    int* ssrc   = (int*)alloc((size_t)NE*4);
    int* sdst   = (int*)alloc((size_t)NE*4);
    int* perm   = (int*)alloc((size_t)NE*4);

    unsigned short* PXS  = PK + 0;        // We1
    unsigned short* PX2  = PK + 16384;    // We2
    unsigned short* PW1  = PK + 32768;    // We3
    unsigned short* PeRZ = PK + 49152;
    unsigned short* PeNI = PK + 114688;
    unsigned short* PeNH = PK + 131072;
    unsigned short* PnP1 = PK + 147456;
    unsigned short* PnRZ = PK + 180224;
    unsigned short* PnNI = PK + 245760;
    unsigned short* PnNH = PK + 262144;

    hipMemsetAsync(histo, 0, (size_t)(NN+NG)*4, stream);
    hist_count<<<(NE+255)/256, 256, 0, stream>>>(dst, batch, histo, cnt);
    scan_kernel<<<1, 256, 0, stream>>>(histo, cursor);
    scatter_kernel<<<(NE+255)/256, 256, 0, stream>>>(src, dst, cursor, ssrc, sdst, perm);
    {
        long groups = (long)(NE+NN+NG)*16;
        conv_all<<<(int)((groups+255)/256), 256, 0, stream>>>(ea_i, perm, x, u, ea, xb, ucur);
    }

    PackJobs PJ;
    auto setj = [&](int t, const float* s0, const float* s1, int ld, int coloff,
                    int kr0, int ktot, int ntot, int base){
        PJ.j[t] = PackJob{ s0, s1, ld, coloff, kr0, ktot, ktot*ntot, base };
    };
    setj(0, We,            We,   Hdim, 0,   128, 128, 128, 0);
    setj(1, We+128*Hdim,   We,   Hdim, 0,   128, 128, 128, 16384);
    setj(2, We+256*Hdim,   We,   Hdim, 0,   128, 128, 128, 32768);
    setj(3, eWih, eWhh, 384, 0,   128, 256, 256, 49152);
    setj(4, eWih, eWih, 384, 256, 128, 128, 128, 114688);
    setj(5, eWhh, eWhh, 384, 256, 128, 128, 128, 131072);
    setj(6, Wn,   Wn,   Hdim, 0,  256, 256, 128, 147456);
    setj(7, nWih, nWhh, 384, 0,   128, 256, 256, 180224);
    setj(8, nWih, nWih, 384, 256, 128, 128, 128, 245760);
    setj(9, nWhh, nWhh, 384, 256, 128, 128, 128, 262144);
    pack_all<<<278528/256, 256, 0, stream>>>(PJ, PK);

    graph_pre_kernel<<<32, 128, 0, stream>>>(ucur, We, be, Wn, bn, gu, nu, xsum);

    for (int t=0; t<3; ++t){
        xs_mfma<<<(NN+EBX-1)/EBX, 256, 0, stream>>>(xb, PXS, gu, batch, xs1g, agg);
        edge_mfma<<<NE/EB, 256, 0, stream>>>(ea, xs1g, xb, PW1, PX2, PeRZ, PeNI, PeNH,
                                             ebih, ebhh, ssrc, sdst, agg);
        node_mfma<<<(NN+NB-1)/NB, 256, 0, stream>>>(xb, agg, nu, PnP1, PnRZ, PnNI, PnNH,
                                                    nbih, nbhh, batch, xsum);
        global_kernel<<<NG, 128, 0, stream>>>(xsum, cnt, ucur, Wg, bg,
                                              gWih, gWhh, gbih, gbhh,
                                              We, be, Wn, bn, gu, nu, out, t);
    }
}